// Round 10
// baseline (210.194 us; speedup 1.0000x reference)
//
#include <hip/hip_runtime.h>

#define C_IN   128
#define H_IN   56
#define W_IN   56
#define HW     3136      // 56*56
#define CHW    401408    // 128*3136
#define O_OUT  256
#define OHW    802816    // 256*3136

#define LDK 72           // fallback padded layout
#define XTP 132          // xt3 transpose LDS row stride (ushorts)

typedef __bf16 bf16x8 __attribute__((ext_vector_type(8)));
typedef float  f32x4  __attribute__((ext_vector_type(4)));
typedef unsigned short ushort_t;
typedef ushort_t ushort8 __attribute__((ext_vector_type(8)));

__device__ __forceinline__ ushort_t f2bf(float f) {
    union { float f; unsigned u; } v; v.f = f;
    unsigned r = (v.u + 0x7fffu + ((v.u >> 16) & 1u)) >> 16;
    return (ushort_t)r;
}

typedef const __attribute__((address_space(1))) unsigned int* gas_ptr;
typedef __attribute__((address_space(3))) unsigned int* las_ptr;
__device__ __forceinline__ void gl_lds16(const void* g, void* l) {
    // async global->LDS, 16B/lane; LDS dest must be wave-uniform
    __builtin_amdgcn_global_load_lds((gas_ptr)g, (las_ptr)l, 16, 0, 0);
}

// ============================ FAST PATH ============================

// Weights -> BK=32 units: wbf[v][o][j2][8] bf16, v = pos*4 + a (36 units of 16 KB).
// Content at slot j2: channel group g2 = j2 ^ ((o>>1)&3)  (4-slot add-free swizzle
// making conv13's A-frag ds_reads 2-way-bank-free at 64 B row stride).
// c = a*32 + g2*8 + e.
__global__ void wt5_kernel(const float* __restrict__ w, ushort_t* __restrict__ wbf) {
    int idx = blockIdx.x * 256 + threadIdx.x;        // 36*8192 = 294912
    if (idx >= 294912) return;
    int v  = idx >> 13;          // 0..35
    int r  = idx & 8191;
    int o  = r >> 5;             // 0..255
    int s  = r & 31;
    int j2 = s >> 3;             // 0..3
    int e  = s & 7;
    int a   = v & 3;
    int pos = v >> 2;
    int g2 = j2 ^ ((o >> 1) & 3);
    int c  = a * 32 + g2 * 8 + e;
    wbf[idx] = f2bf(w[o * 1152 + c * 9 + pos]);
}

// x fp32 NCHW -> padded swizzled bf16 NHWC: xbp[n][h'][w'][a][slot2][8],
// h',w' in [0,58), borders zero. Within-row: chunk a = c>>5 is LINEAR (64 B);
// within chunk, slot2 = g2 ^ k(w'), k(w') = (w'&3)^((w'>>2)&3), g2 = (c>>3)&3.
// Linear 64-B staging per pixel-chunk; read deswizzles with the same key.
__global__ __launch_bounds__(256)
void xt3_kernel(const float* __restrict__ x, ushort_t* __restrict__ xbp) {
    const int b  = blockIdx.x;            // 0..1855  (32*58)
    const int n  = b / 58;
    const int hp = b - n * 58;
    ushort_t* orow = xbp + (size_t)(n * 58 + hp) * 7424;
    const int t = threadIdx.x;
    ushort8 z = ushort8{0,0,0,0,0,0,0,0};

    if (hp == 0 || hp == 57) {
        #pragma unroll
        for (int i = 0; i < 4; ++i) {
            int u = i * 256 + t;
            if (u < 928) *(ushort8*)(orow + u * 8) = z;
        }
        return;
    }

    __shared__ ushort_t T[56 * XTP];      // [w][c], 14784 B
    const int h = hp - 1;
    const float* src = x + (size_t)n * CHW + h * W_IN;
    #pragma unroll
    for (int i = 0; i < 7; ++i) {
        int g  = i * 256 + t;             // 0..1791 = 128 ch * 14 float4
        int c  = g / 14;
        int f4 = g - c * 14;
        f32x4 v = *(const f32x4*)(src + (size_t)c * HW + f4 * 4);
        #pragma unroll
        for (int j = 0; j < 4; ++j)
            T[(f4 * 4 + j) * XTP + c] = f2bf(v[j]);
    }
    __syncthreads();
    #pragma unroll
    for (int i = 0; i < 4; ++i) {
        int u = i * 256 + t;              // 0..927 = 58 w' * 16 groups
        if (u < 928) {
            int wp = u >> 4, gg = u & 15;
            ushort8 v = (wp == 0 || wp == 57) ? z
                        : *(const ushort8*)(&T[(wp - 1) * XTP + gg * 8]);
            const int a  = gg >> 2;
            const int g2 = gg & 3;
            const int k  = (wp & 3) ^ ((wp >> 2) & 3);
            *(ushort8*)(orow + wp * 128 + ((a * 4 + (g2 ^ k)) << 3)) = v;
        }
    }
}

// conv13: counted-vmcnt pipelined implicit GEMM (derived-waits port of the
// 8-phase mechanism at conv12's proven addressing discipline).
//  - tile 256o x 128px, 512 thr / 8 waves (wm=wave>>1 o-slice 64, wn=wave&1 px-half 64)
//  - 36 BK=32 units; A 16 KB + B 8 KB per unit via 3-slot LDS rings (72 KB -> 2 blk/CU)
//  - per unit: 8 ds_read + issue q+2 (3 gl_lds) -> s_barrier -> lgkmcnt(0) ->
//    setprio + 16 MFMA -> vmcnt(3) -> s_barrier.  Loads for q+2 stay in flight
//    across BOTH barriers; never drain in-loop (m218 counted-vs-drain lever).
__global__ __launch_bounds__(512, 4)
void conv13_kernel(const ushort_t* __restrict__ xbp, const ushort_t* __restrict__ wbf,
                   const float* __restrict__ bias, float* __restrict__ out) {
    __shared__ ushort_t Alds[3][8192];   // 48 KB  [o][slot2^][8] per 16 KB unit
    __shared__ ushort_t Blds[3][4096];   // 24 KB  [px][slot2^][8] per 8 KB unit

    const int tid  = threadIdx.x;
    const int lane = tid & 63;
    const int wave = tid >> 6;      // 0..7
    const int wm   = wave >> 1;     // 0..3  o-slice (64)
    const int wn   = wave & 1;      // 0..1  px-half (64)
    const int l15  = lane & 15;
    const int quad = lane >> 4;
    const int wb10 = wave << 10;    // wave-uniform 1 KB stride for gl_lds dests

    // block -> 128-px tile; XCD-aware bijective swizzle (784 = 8*98)
    int b = blockIdx.x;
    b = (b & 7) * 98 + (b >> 3);
    const int pix_base = b * 128;

    // ---- A-frag LDS byte offsets (static per lane) ----
    int aoff[4];
    #pragma unroll
    for (int t = 0; t < 4; ++t) {
        int o = wm * 64 + t * 16 + l15;
        aoff[t] = o * 64 + ((quad ^ ((o >> 1) & 3)) << 4);
    }

    // ---- B-frag per-lane geometry ----
    int pxb[4], w1[4];
    #pragma unroll
    for (int u = 0; u < 4; ++u) {
        int px = wn * 64 + u * 16 + l15;
        int p  = pix_base + px;
        int n_ = p / HW;
        int hw = p - n_ * HW;
        int h  = hw / W_IN;
        int w_ = hw - h * W_IN;
        pxb[u] = px * 64;
        w1[u]  = w_ + 1;
    }

    // ---- B staging per-lane source base (byte offset into xbp) ----
    int Brow;
    {
        int spx = tid >> 2;          // 0..127
        int j2  = tid & 3;
        int sp  = pix_base + spx;
        int sn  = sp / HW;
        int shw = sp - sn * HW;
        int sh  = shw / W_IN;
        int sw  = shw - sh * W_IN;
        Brow = ((sn * 58 + sh + 1) * 58 + (sw + 1)) * 256 + j2 * 16;
    }

    f32x4 acc[4][4];
    #pragma unroll
    for (int t = 0; t < 4; ++t)
        #pragma unroll
        for (int u = 0; u < 4; ++u)
            acc[t][u] = f32x4{0.f, 0.f, 0.f, 0.f};

    const char* wgb = (const char*)wbf;
    const char* xgb = (const char*)xbp;

    char* A0 = (char*)Alds[0]; char* A1 = (char*)Alds[1]; char* A2 = (char*)Alds[2];
    char* B0 = (char*)Blds[0]; char* B1 = (char*)Blds[1]; char* B2 = (char*)Blds[2];

#define ISSUE(vv, Ad, Bd) { \
    const int v_ = (vv); \
    const int pos_ = v_ >> 2, a_ = v_ & 3; \
    const int dh_ = pos_ / 3 - 1; \
    const int dw_ = pos_ - (pos_ / 3) * 3 - 1; \
    const char* as_ = wgb + (size_t)v_ * 16384; \
    gl_lds16(as_ + wb10 + (lane << 4),        (Ad) + wb10); \
    gl_lds16(as_ + 8192 + wb10 + (lane << 4), (Ad) + 8192 + wb10); \
    const int soff_ = (dh_ * 58 + dw_) * 256 + a_ * 64; \
    gl_lds16(xgb + (long)(Brow + soff_),      (Bd) + wb10); }

    // prologue: units 0,1 into ring slots 0,1; wait unit0 landed (counted)
    ISSUE(0, A0, B0);
    ISSUE(1, A1, B1);
    asm volatile("s_waitcnt vmcnt(3)" ::: "memory");
    __builtin_amdgcn_s_barrier();

    for (int q = 0; q < 36; ++q) {
        const int pos = q >> 2;
        const int dw  = pos - (pos / 3) * 3 - 1;

        // fragment reads from current slots (complete at lgkmcnt below)
        bf16x8 af[4], bf[4];
        #pragma unroll
        for (int t = 0; t < 4; ++t)
            af[t] = *(const bf16x8*)(A0 + aoff[t]);
        #pragma unroll
        for (int u = 0; u < 4; ++u) {
            const int ww  = w1[u] + dw;
            const int key = (ww & 3) ^ ((ww >> 2) & 3);
            bf[u] = *(const bf16x8*)(B0 + pxb[u] + ((quad ^ key) << 4));
        }

        // prefetch unit q+2 into the slot freed after unit q-1
        if (q < 34) ISSUE(q + 2, A2, B2);

        __builtin_amdgcn_s_barrier();
        asm volatile("s_waitcnt lgkmcnt(0)" ::: "memory");
        __builtin_amdgcn_sched_barrier(0);
        __builtin_amdgcn_s_setprio(1);
        #pragma unroll
        for (int t = 0; t < 4; ++t)
            #pragma unroll
            for (int u = 0; u < 4; ++u)
                acc[t][u] = __builtin_amdgcn_mfma_f32_16x16x32_bf16(
                                af[t], bf[u], acc[t][u], 0, 0, 0);
        __builtin_amdgcn_s_setprio(0);
        __builtin_amdgcn_sched_barrier(0);

        // counted wait: unit q+1 landed; unit q+2 stays in flight across barrier
        if (q < 34) asm volatile("s_waitcnt vmcnt(3)" ::: "memory");
        else        asm volatile("s_waitcnt vmcnt(0)" ::: "memory");
        __builtin_amdgcn_s_barrier();

        // rotate rings
        char* tA = A0; A0 = A1; A1 = A2; A2 = tA;
        char* tB = B0; B0 = B1; B1 = B2; B2 = tB;
    }
#undef ISSUE

    // ---- epilogue (conv12-proven mapping) ----
    f32x4 bv[4];
    #pragma unroll
    for (int t = 0; t < 4; ++t)
        bv[t] = *(const f32x4*)(bias + wm * 64 + t * 16 + quad * 4);
    #pragma unroll
    for (int u = 0; u < 4; ++u) {
        const int px  = wn * 64 + u * 16 + l15;
        const int p   = pix_base + px;
        const int nn  = p / HW;
        const int hw2 = p - nn * HW;
        float* op = out + (size_t)nn * OHW + hw2;
        #pragma unroll
        for (int t = 0; t < 4; ++t) {
            const int o0 = wm * 64 + t * 16 + quad * 4;
            #pragma unroll
            for (int r = 0; r < 4; ++r)
                op[(size_t)(o0 + r) * HW] = acc[t][u][r] + bv[t][r];
        }
    }
}

// ============================ FALLBACK (known-correct) ============================

__global__ void wt_kernel(const float* __restrict__ w, ushort_t* __restrict__ wbf) {
    int idx = blockIdx.x * 256 + threadIdx.x;        // 9*256*128 = 294912
    if (idx >= 9 * 256 * 128) return;
    int pos = idx >> 15;
    int rem = idx & 32767;
    int o   = rem >> 7;
    int c   = rem & 127;
    wbf[idx] = f2bf(w[o * 1152 + c * 9 + pos]);
}

__global__ __launch_bounds__(512, 4)
void conv_kernel(const float* __restrict__ x, const ushort_t* __restrict__ wbf,
                 const float* __restrict__ bias, float* __restrict__ out) {
    __shared__ ushort_t As[256 * LDK];
    __shared__ ushort_t Bs[128 * LDK];

    const int tid  = threadIdx.x;
    const int lane = tid & 63;
    const int wave = tid >> 6;
    const int wm   = wave >> 1;
    const int wn   = wave & 1;
    const int l15  = lane & 15;
    const int quad = lane >> 4;

    const int pix_base = blockIdx.x * 128;
    const int px  = tid & 127;
    const int cg0 = tid >> 7;
    const int p   = pix_base + px;
    const int n_img = p / HW;
    const int hw    = p - n_img * HW;
    const int h     = hw / W_IN;
    const int w_    = hw - h * W_IN;
    const float* ximg = x + (long)n_img * CHW;

    f32x4 acc[4][4];
    #pragma unroll
    for (int t = 0; t < 4; ++t)
        #pragma unroll
        for (int u = 0; u < 4; ++u)
            acc[t][u] = f32x4{0.f, 0.f, 0.f, 0.f};

    for (int pos = 0; pos < 9; ++pos) {
        const int dh = pos / 3 - 1;
        const int dw = pos - (pos / 3) * 3 - 1;
        const int ih = h + dh;
        const int iw = w_ + dw;
        const bool valid = ((unsigned)ih < (unsigned)H_IN) && ((unsigned)iw < (unsigned)W_IN);
        const float* xsrc = ximg + ih * W_IN + iw;

        for (int half = 0; half < 2; ++half) {
            const int c0 = half * 64;
            {
                const ushort_t* wsrc = wbf + ((pos * 256) << 7) + c0;
                #pragma unroll
                for (int sj = 0; sj < 4; ++sj) {
                    const int o  = (tid >> 3) + sj * 64;
                    const int cg = tid & 7;
                    ushort8 v = *(const ushort8*)(wsrc + (o << 7) + cg * 8);
                    *(ushort8*)(&As[o * LDK + cg * 8]) = v;
                }
            }
            {
                #pragma unroll
                for (int sj = 0; sj < 2; ++sj) {
                    const int cg = cg0 + sj * 4;
                    const float* src = xsrc + (long)(c0 + cg * 8) * HW;
                    ushort8 v;
                    #pragma unroll
                    for (int j = 0; j < 8; ++j) {
                        float f = valid ? src[j * HW] : 0.0f;
                        v[j] = f2bf(f);
                    }
                    *(ushort8*)(&Bs[px * LDK + cg * 8]) = v;
                }
            }
            __syncthreads();

            #pragma unroll
            for (int ks = 0; ks < 2; ++ks) {
                bf16x8 af[4], bfv[4];
                #pragma unroll
                for (int t = 0; t < 4; ++t) {
                    const int row = wm * 64 + t * 16 + l15;
                    af[t] = *(const bf16x8*)(&As[row * LDK + ks * 32 + quad * 8]);
                }
                #pragma unroll
                for (int u = 0; u < 4; ++u) {
                    const int col = wn * 64 + u * 16 + l15;
                    bfv[u] = *(const bf16x8*)(&Bs[col * LDK + ks * 32 + quad * 8]);
                }
                #pragma unroll
                for (int t = 0; t < 4; ++t)
                    #pragma unroll
                    for (int u = 0; u < 4; ++u)
                        acc[t][u] = __builtin_amdgcn_mfma_f32_16x16x32_bf16(af[t], bfv[u], acc[t][u], 0, 0, 0);
            }
            __syncthreads();
        }
    }

    #pragma unroll
    for (int u = 0; u < 4; ++u) {
        const int col = wn * 64 + u * 16 + l15;
        const int pp  = pix_base + col;
        const int hw2 = pp - (pp / HW) * HW;
        const long obase = (long)(pp / HW) * OHW + hw2;
        #pragma unroll
        for (int t = 0; t < 4; ++t) {
            const int o_base = wm * 64 + t * 16 + quad * 4;
            #pragma unroll
            for (int r = 0; r < 4; ++r) {
                const int o = o_base + r;
                out[obase + (long)o * HW] = acc[t][u][r] + bias[o];
            }
        }
    }
}

extern "C" void kernel_launch(void* const* d_in, const int* in_sizes, int n_in,
                              void* d_out, int out_size, void* d_ws, size_t ws_size,
                              hipStream_t stream) {
    const float* x    = (const float*)d_in[0];
    const float* w    = (const float*)d_in[1];
    const float* bias = (const float*)d_in[2];
    float* out        = (float*)d_out;

    // fast path: wbf (589,824 B) + xbp (padded 58x58 NHWC, 27,557,888 B)
    const size_t NEED_NEW = 589824u + 27557888u;    // 28,147,712

    if (ws_size >= NEED_NEW) {
        ushort_t* wbf = (ushort_t*)d_ws;
        ushort_t* xbp = (ushort_t*)((char*)d_ws + 589824);
        hipLaunchKernelGGL(wt5_kernel, dim3(1152), dim3(256), 0, stream, w, wbf);
        hipLaunchKernelGGL(xt3_kernel, dim3(1856), dim3(256), 0, stream, x, xbp);
        hipLaunchKernelGGL(conv13_kernel, dim3(784), dim3(512), 0, stream,
                           xbp, wbf, bias, out);
    } else {
        ushort_t* wbf = (ushort_t*)d_ws;
        hipLaunchKernelGGL(wt_kernel, dim3(1152), dim3(256), 0, stream, w, wbf);
        hipLaunchKernelGGL(conv_kernel, dim3(100352 / 128), dim3(512), 0, stream,
                           x, wbf, bias, out);
    }
}